// Round 2
// baseline (18761.119 us; speedup 1.0000x reference)
//
#include <hip/hip_runtime.h>
#include <hip/hip_bf16.h>

#define S_LEN 4096
#define DIM   256
#define HID   512
#define G4    2048
#define NE    2000
#define NL    20
#define KWG   16   // workgroups per direction in persistent LSTM

__device__ __forceinline__ float sigmoidf_(float x) { return 1.f / (1.f + expf(-x)); }

// ---------------------------------------------------------------------------
// Kernel 1: input projection  xw[dir][t][j] = sum_k emb[sentence[t]][k]*Wi[j][k] + b[j]
// ---------------------------------------------------------------------------
__global__ __launch_bounds__(256) void xw_gemm(const int* __restrict__ sentence,
                                               const float* __restrict__ emb,
                                               const float* __restrict__ Wi_f,
                                               const float* __restrict__ b_f,
                                               const float* __restrict__ Wi_b,
                                               const float* __restrict__ b_b,
                                               float* __restrict__ xwf,
                                               float* __restrict__ xwb)
{
    const int tblk = blockIdx.x, jblk = blockIdx.y, dir = blockIdx.z;
    const float* Wi = dir ? Wi_b : Wi_f;
    const float* bb = dir ? b_b : b_f;
    float* xw = dir ? xwb : xwf;

    __shared__ float4 xs[16][64];   // 16 rows of x, 256 floats each (16 KB)
    const int tid = threadIdx.x;
    {
        const int r = tid >> 4, q0 = tid & 15;
        const int srow = sentence[tblk * 16 + r];
        const float4* er = (const float4*)(emb + (size_t)srow * DIM);
#pragma unroll
        for (int q = 0; q < 4; ++q) xs[r][q0 * 4 + q] = er[q0 * 4 + q];
    }
    __syncthreads();

    float acc[16][4];
#pragma unroll
    for (int t = 0; t < 16; ++t)
#pragma unroll
        for (int q = 0; q < 4; ++q) acc[t][q] = 0.f;

    const float4* Wi4 = (const float4*)Wi;
    const int j0 = jblk * 1024 + tid;
    for (int kk = 0; kk < 64; ++kk) {
        float4 wv0 = Wi4[(j0)*64 + kk];
        float4 wv1 = Wi4[(j0 + 256) * 64 + kk];
        float4 wv2 = Wi4[(j0 + 512) * 64 + kk];
        float4 wv3 = Wi4[(j0 + 768) * 64 + kk];
#pragma unroll
        for (int t = 0; t < 16; ++t) {
            float4 xv = xs[t][kk];
            acc[t][0] = fmaf(xv.x, wv0.x, fmaf(xv.y, wv0.y, fmaf(xv.z, wv0.z, fmaf(xv.w, wv0.w, acc[t][0]))));
            acc[t][1] = fmaf(xv.x, wv1.x, fmaf(xv.y, wv1.y, fmaf(xv.z, wv1.z, fmaf(xv.w, wv1.w, acc[t][1]))));
            acc[t][2] = fmaf(xv.x, wv2.x, fmaf(xv.y, wv2.y, fmaf(xv.z, wv2.z, fmaf(xv.w, wv2.w, acc[t][2]))));
            acc[t][3] = fmaf(xv.x, wv3.x, fmaf(xv.y, wv3.y, fmaf(xv.z, wv3.z, fmaf(xv.w, wv3.w, acc[t][3]))));
        }
    }
#pragma unroll
    for (int q = 0; q < 4; ++q) {
        const int j = j0 + q * 256;
        const float bj = bb[j];
#pragma unroll
        for (int t = 0; t < 16; ++t)
            xw[(size_t)(tblk * 16 + t) * G4 + j] = acc[t][q] + bj;
    }
}

// ---------------------------------------------------------------------------
// Kernel 2: persistent BiLSTM. 32 WGs (16/dir), 256 threads.
// Per-WG flag lines (no contended RMW); relaxed-poll + one acquire fence per
// step; h published with write-through agent stores and read straight into
// registers (no LDS staging); xw prefetched under the wait.
// ---------------------------------------------------------------------------
__global__ __launch_bounds__(256, 1) void lstm_kernel(const float* __restrict__ xwf,
                                                      const float* __restrict__ xwb,
                                                      const float* __restrict__ Wh_f,
                                                      const float* __restrict__ Wh_b,
                                                      float* __restrict__ hf,
                                                      float* __restrict__ hb,
                                                      unsigned* __restrict__ flg)
{
    const int wg = blockIdx.x & (KWG - 1);
    const int dir = blockIdx.x >> 4;
    const float* xw = dir ? xwb : xwf;
    const float* Wh = dir ? Wh_b : Wh_f;
    float* hout = dir ? hb : hf;
    unsigned* flgd = flg + (size_t)dir * KWG * 16;   // 16-dword (64B) spacing

    const int tid = threadIdx.x;
    const int wv = tid >> 6;          // wave 0..3  == gate index
    const int ln = tid & 63;
    const int cchunk = ln & 7;        // 8 column chunks of 64
    const int rl = ln >> 3;           // 8 row groups of 4 rows per wave

    // weights: rows = wv*512 + wg*32 + rl*4 + m, cols = cchunk*64 .. +64
    float wreg[4][64];
    {
        const float* wb = Wh + (size_t)(wv * HID + wg * 32 + rl * 4) * HID + cchunk * 64;
#pragma unroll
        for (int m = 0; m < 4; ++m) {
            const float4* w4 = (const float4*)(wb + m * HID);
#pragma unroll
            for (int kk = 0; kk < 16; ++kk) {
                float4 v = w4[kk];
                wreg[m][kk * 4 + 0] = v.x;
                wreg[m][kk * 4 + 1] = v.y;
                wreg[m][kk * 4 + 2] = v.z;
                wreg[m][kk * 4 + 3] = v.w;
            }
        }
    }

    __shared__ float zsh[128];      // [gate*32 + hloc] pre-activations
    float cst = 0.f;                // cell state (wave0 lanes 0..31)
    __syncthreads();

    for (int s = 0; s < S_LEN; ++s) {
        const int t = dir ? (S_LEN - 1 - s) : s;
        const int tprev = dir ? (t + 1) : (t - 1);

        // prefetch this step's xw slice before the wait (independent of h)
        float xwv0 = 0.f, xwv1 = 0.f, xwv2 = 0.f, xwv3 = 0.f;
        if (tid < 32) {
            const float* xr = xw + (size_t)t * G4 + wg * 32 + tid;
            xwv0 = xr[0];
            xwv1 = xr[512];
            xwv2 = xr[1024];
            xwv3 = xr[1536];
            asm volatile("" :: "v"(xwv0), "v"(xwv1), "v"(xwv2), "v"(xwv3));
        }

        // wait for all 16 slices of h[t_prev]: every wave polls independently
        if (s > 0) {
            if (ln < KWG) {
                while (__hip_atomic_load(flgd + ln * 16, __ATOMIC_RELAXED,
                                         __HIP_MEMORY_SCOPE_AGENT) < (unsigned)s) {}
            }
            __builtin_amdgcn_fence(__ATOMIC_ACQUIRE, "agent");
        }

        // h_prev -> registers (broadcast across the 8 lanes sharing a chunk)
        float hreg[64];
        if (s > 0) {
            const float4* hp4 = (const float4*)(hout + (size_t)tprev * HID + cchunk * 64);
#pragma unroll
            for (int kk = 0; kk < 16; ++kk) {
                float4 v = hp4[kk];
                hreg[kk * 4 + 0] = v.x;
                hreg[kk * 4 + 1] = v.y;
                hreg[kk * 4 + 2] = v.z;
                hreg[kk * 4 + 3] = v.w;
            }
        } else {
#pragma unroll
            for (int q = 0; q < 64; ++q) hreg[q] = 0.f;
        }

        // matvec partials: 4 rows x 64 cols per thread
        float s0 = 0.f, s1 = 0.f, s2 = 0.f, s3 = 0.f;
#pragma unroll
        for (int q = 0; q < 64; ++q) {
            const float hv = hreg[q];
            s0 = fmaf(wreg[0][q], hv, s0);
            s1 = fmaf(wreg[1][q], hv, s1);
            s2 = fmaf(wreg[2][q], hv, s2);
            s3 = fmaf(wreg[3][q], hv, s3);
        }
        // reduce over the 8 column-chunk lanes
#pragma unroll
        for (int off = 1; off < 8; off <<= 1) {
            s0 += __shfl_xor(s0, off);
            s1 += __shfl_xor(s1, off);
            s2 += __shfl_xor(s2, off);
            s3 += __shfl_xor(s3, off);
        }
        if ((ln & 7) == 0) {
            zsh[wv * 32 + rl * 4 + 0] = s0;
            zsh[wv * 32 + rl * 4 + 1] = s1;
            zsh[wv * 32 + rl * 4 + 2] = s2;
            zsh[wv * 32 + rl * 4 + 3] = s3;
        }
        __syncthreads();   // zsh ready for wave0

        // gates + publish (wave0 lanes 0..31). zsh reuse next step is safe:
        // other waves only rewrite zsh after seeing our flag (set below).
        if (tid < 32) {
            const float zi = zsh[tid] + xwv0;
            const float zf = zsh[32 + tid] + xwv1;
            const float zg = zsh[64 + tid] + xwv2;
            const float zo = zsh[96 + tid] + xwv3;
            const float ig = sigmoidf_(zi);
            const float fg = sigmoidf_(zf);
            const float og = sigmoidf_(zo);
            const float gg = tanhf(zg);
            cst = fg * cst + ig * gg;
            const float hv = og * tanhf(cst);
            // write-through agent store: visible at LLC, no dirty L2 line
            __hip_atomic_store(hout + (size_t)t * HID + wg * 32 + tid, hv,
                               __ATOMIC_RELAXED, __HIP_MEMORY_SCOPE_AGENT);
        }
        if (tid == 0) {
            __builtin_amdgcn_fence(__ATOMIC_RELEASE, "agent");
            __hip_atomic_store(flgd + wg * 16, (unsigned)(s + 1),
                               __ATOMIC_RELAXED, __HIP_MEMORY_SCOPE_AGENT);
        }
        // no trailing barrier: waves re-sync via the flag poll next step
    }
}

// ---------------------------------------------------------------------------
// Kernel 3: scores[t] = blstm[t] . attn_w + attn_b
// ---------------------------------------------------------------------------
__global__ __launch_bounds__(256) void score_kernel(const float* __restrict__ hf,
                                                    const float* __restrict__ hb,
                                                    const float* __restrict__ aw,
                                                    const float* __restrict__ ab,
                                                    float* __restrict__ scores)
{
    const int t = blockIdx.x;
    const int tid = threadIdx.x;
    float p = hf[(size_t)t * HID + tid] * aw[tid]
            + hf[(size_t)t * HID + 256 + tid] * aw[256 + tid]
            + hb[(size_t)t * HID + tid] * aw[512 + tid]
            + hb[(size_t)t * HID + 256 + tid] * aw[768 + tid];
#pragma unroll
    for (int off = 1; off < 64; off <<= 1) p += __shfl_xor(p, off);
    __shared__ float rsum[4];
    if ((tid & 63) == 0) rsum[tid >> 6] = p;
    __syncthreads();
    if (tid == 0) scores[t] = rsum[0] + rsum[1] + rsum[2] + rsum[3] + ab[0];
}

// ---------------------------------------------------------------------------
// Kernel 4: per-entity masked softmax over span scores + weighted sum of blstm
// ---------------------------------------------------------------------------
__global__ __launch_bounds__(256) void entity_kernel(const int* __restrict__ eidx,
                                                     const float* __restrict__ scores,
                                                     const float* __restrict__ hf,
                                                     const float* __restrict__ hb,
                                                     float* __restrict__ out)
{
    const int e = blockIdx.x;
    const int tid = threadIdx.x;
    __shared__ float wsh[NL];
    __shared__ int ish[NL];
    if (tid < 32) {
        const int l = tid;
        const int ix = (l < NL) ? eidx[e * NL + l] : -1;
        const float sc = (ix >= 0) ? scores[ix] : -1e9f;
        float mx = sc;
#pragma unroll
        for (int off = 1; off < 32; off <<= 1) mx = fmaxf(mx, __shfl_xor(mx, off));
        const float ex = (ix >= 0) ? expf(sc - mx) : 0.f;
        float sm = ex;
#pragma unroll
        for (int off = 1; off < 32; off <<= 1) sm += __shfl_xor(sm, off);
        if (l < NL) {
            wsh[l] = ex / sm;
            ish[l] = (ix >= 0) ? ix : 0;
        }
    }
    __syncthreads();
    for (int d0 = tid; d0 < 1024; d0 += 256) {
        const float* hsrc = (d0 < HID) ? hf : hb;
        const int dd = d0 & (HID - 1);
        float a = 0.f;
#pragma unroll
        for (int l = 0; l < NL; ++l) a += wsh[l] * hsrc[(size_t)ish[l] * HID + dd];
        out[(size_t)e * 1024 + d0] = a;
    }
}

// ---------------------------------------------------------------------------
extern "C" void kernel_launch(void* const* d_in, const int* in_sizes, int n_in,
                              void* d_out, int out_size, void* d_ws, size_t ws_size,
                              hipStream_t stream)
{
    const int*   sentence = (const int*)d_in[0];
    const int*   eidx     = (const int*)d_in[1];
    const float* emb      = (const float*)d_in[2];
    const float* Wi_f     = (const float*)d_in[3];
    const float* Wh_f     = (const float*)d_in[4];
    const float* b_f      = (const float*)d_in[5];
    const float* Wi_b     = (const float*)d_in[6];
    const float* Wh_b     = (const float*)d_in[7];
    const float* b_b      = (const float*)d_in[8];
    const float* attn_w   = (const float*)d_in[9];
    const float* attn_b   = (const float*)d_in[10];
    float* out = (float*)d_out;
    float* ws  = (float*)d_ws;

    // workspace layout (floats): xwf | xwb | hf | hb | scores | flags
    const size_t XW = (size_t)S_LEN * G4;   // 8388608 floats per direction
    const size_t HS = (size_t)S_LEN * HID;  // 2097152 floats per direction
    float* xwf = ws;
    float* xwb = ws + XW;
    float* hf  = ws + 2 * XW;
    float* hb  = ws + 2 * XW + HS;
    float* sc  = ws + 2 * XW + 2 * HS;
    unsigned* flg = (unsigned*)(ws + 2 * XW + 2 * HS + S_LEN);

    hipMemsetAsync(flg, 0, 2 * KWG * 16 * sizeof(unsigned), stream);
    xw_gemm<<<dim3(256, 2, 2), dim3(256), 0, stream>>>(sentence, emb, Wi_f, b_f, Wi_b, b_b, xwf, xwb);
    lstm_kernel<<<dim3(2 * KWG), dim3(256), 0, stream>>>(xwf, xwb, Wh_f, Wh_b, hf, hb, flg);
    score_kernel<<<dim3(S_LEN), dim3(256), 0, stream>>>(hf, hb, attn_w, attn_b, sc);
    entity_kernel<<<dim3(NE), dim3(256), 0, stream>>>(eidx, sc, hf, hb, out);
}

// Round 4
// 16438.058 us; speedup vs baseline: 1.1413x; 1.1413x over previous
//
#include <hip/hip_runtime.h>
#include <hip/hip_bf16.h>

#define S_LEN 4096
#define DIM   256
#define HID   512
#define G4    2048
#define NE    2000
#define NL    20
#define KWG   16   // workgroups per direction in persistent LSTM

__device__ __forceinline__ float sigmoidf_(float x) { return 1.f / (1.f + expf(-x)); }

// ---------------------------------------------------------------------------
// Kernel 1: input projection  xw[dir][t][j] = sum_k emb[sentence[t]][k]*Wi[j][k] + b[j]
// ---------------------------------------------------------------------------
__global__ __launch_bounds__(256) void xw_gemm(const int* __restrict__ sentence,
                                               const float* __restrict__ emb,
                                               const float* __restrict__ Wi_f,
                                               const float* __restrict__ b_f,
                                               const float* __restrict__ Wi_b,
                                               const float* __restrict__ b_b,
                                               float* __restrict__ xwf,
                                               float* __restrict__ xwb)
{
    const int tblk = blockIdx.x, jblk = blockIdx.y, dir = blockIdx.z;
    const float* Wi = dir ? Wi_b : Wi_f;
    const float* bb = dir ? b_b : b_f;
    float* xw = dir ? xwb : xwf;

    __shared__ float4 xs[16][64];
    const int tid = threadIdx.x;
    {
        const int r = tid >> 4, q0 = tid & 15;
        const int srow = sentence[tblk * 16 + r];
        const float4* er = (const float4*)(emb + (size_t)srow * DIM);
#pragma unroll
        for (int q = 0; q < 4; ++q) xs[r][q0 * 4 + q] = er[q0 * 4 + q];
    }
    __syncthreads();

    float acc[16][4];
#pragma unroll
    for (int t = 0; t < 16; ++t)
#pragma unroll
        for (int q = 0; q < 4; ++q) acc[t][q] = 0.f;

    const float4* Wi4 = (const float4*)Wi;
    const int j0 = jblk * 1024 + tid;
    for (int kk = 0; kk < 64; ++kk) {
        float4 wv0 = Wi4[(j0)*64 + kk];
        float4 wv1 = Wi4[(j0 + 256) * 64 + kk];
        float4 wv2 = Wi4[(j0 + 512) * 64 + kk];
        float4 wv3 = Wi4[(j0 + 768) * 64 + kk];
#pragma unroll
        for (int t = 0; t < 16; ++t) {
            float4 xv = xs[t][kk];
            acc[t][0] = fmaf(xv.x, wv0.x, fmaf(xv.y, wv0.y, fmaf(xv.z, wv0.z, fmaf(xv.w, wv0.w, acc[t][0]))));
            acc[t][1] = fmaf(xv.x, wv1.x, fmaf(xv.y, wv1.y, fmaf(xv.z, wv1.z, fmaf(xv.w, wv1.w, acc[t][1]))));
            acc[t][2] = fmaf(xv.x, wv2.x, fmaf(xv.y, wv2.y, fmaf(xv.z, wv2.z, fmaf(xv.w, wv2.w, acc[t][2]))));
            acc[t][3] = fmaf(xv.x, wv3.x, fmaf(xv.y, wv3.y, fmaf(xv.z, wv3.z, fmaf(xv.w, wv3.w, acc[t][3]))));
        }
    }
#pragma unroll
    for (int q = 0; q < 4; ++q) {
        const int j = j0 + q * 256;
        const float bj = bb[j];
#pragma unroll
        for (int t = 0; t < 16; ++t)
            xw[(size_t)(tblk * 16 + t) * G4 + j] = acc[t][q] + bj;
    }
}

// ---------------------------------------------------------------------------
// Kernel 2: persistent BiLSTM. 32 WGs (16/dir), 512 threads (8 waves).
// Wave w owns h-elems [wg*32 + w*4, +4), all 4 gates. Per thread: 4 gate-rows
// x 32 cols -> 128 weight floats in VGPRs (NO spill). Zero LDS in step loop.
// Protocol per step: store h -> __syncthreads (drains stores) -> tid0:
// agent-release fence (wbL2) + per-WG flag store -> all waves prefetch next
// xw (hides under poll) -> wave0 lanes 0..15 poll all 16 flags RELAXED with
// s_sleep backoff -> one agent-acquire fence -> __syncthreads -> h loads.
// ---------------------------------------------------------------------------
__global__ __launch_bounds__(512, 2) void lstm_kernel(const float* __restrict__ xwf,
                                                      const float* __restrict__ xwb,
                                                      const float* __restrict__ Wh_f,
                                                      const float* __restrict__ Wh_b,
                                                      float* __restrict__ hf,
                                                      float* __restrict__ hb,
                                                      unsigned* __restrict__ flg)
{
    const int wg = blockIdx.x & (KWG - 1);
    const int dir = blockIdx.x >> 4;
    const float* xw = dir ? xwb : xwf;
    const float* Wh = dir ? Wh_b : Wh_f;
    float* hout = dir ? hb : hf;
    unsigned* flgd = flg + (size_t)dir * KWG * 16;   // 16 flags, 64B apart

    const int tid = threadIdx.x;
    const int w = tid >> 6;           // wave 0..7
    const int ln = tid & 63;
    const int cchunk = ln & 15;       // 16 column chunks of 32
    const int rgrp = ln >> 4;         // 4 elems per wave
    const int e = wg * 32 + w * 4 + rgrp;   // owned h element

    // weights: 4 gate-rows of element e, cols [cchunk*32, +32)
    float wr[4][32];
#pragma unroll
    for (int g = 0; g < 4; ++g) {
        const float4* p = (const float4*)(Wh + (size_t)(g * HID + e) * HID + cchunk * 32);
#pragma unroll
        for (int q = 0; q < 8; ++q) {
            float4 v = p[q];
            wr[g][q * 4 + 0] = v.x; wr[g][q * 4 + 1] = v.y;
            wr[g][q * 4 + 2] = v.z; wr[g][q * 4 + 3] = v.w;
        }
    }

    float cst = 0.f;

    // xw for step 0
    const int t0 = dir ? (S_LEN - 1) : 0;
    float xv0 = xw[(size_t)t0 * G4 + e];
    float xv1 = xw[(size_t)t0 * G4 + 512 + e];
    float xv2 = xw[(size_t)t0 * G4 + 1024 + e];
    float xv3 = xw[(size_t)t0 * G4 + 1536 + e];

    for (int s = 0; s < S_LEN; ++s) {
        const int t = dir ? (S_LEN - 1 - s) : s;
        const int tprev = dir ? (t + 1) : (t - 1);

        float z0 = 0.f, z1 = 0.f, z2 = 0.f, z3 = 0.f;
        if (s > 0) {
            // h_prev -> registers (32 floats per thread)
            const float4* hp = (const float4*)(hout + (size_t)tprev * HID + cchunk * 32);
            float hr[32];
#pragma unroll
            for (int q = 0; q < 8; ++q) {
                float4 v = hp[q];
                hr[q * 4 + 0] = v.x; hr[q * 4 + 1] = v.y;
                hr[q * 4 + 2] = v.z; hr[q * 4 + 3] = v.w;
            }
#pragma unroll
            for (int q = 0; q < 32; ++q) {
                const float hv = hr[q];
                z0 = fmaf(wr[0][q], hv, z0);
                z1 = fmaf(wr[1][q], hv, z1);
                z2 = fmaf(wr[2][q], hv, z2);
                z3 = fmaf(wr[3][q], hv, z3);
            }
            // reduce over the 16 column-chunk lanes (lane bits 0..3)
#pragma unroll
            for (int off = 1; off < 16; off <<= 1) {
                z0 += __shfl_xor(z0, off);
                z1 += __shfl_xor(z1, off);
                z2 += __shfl_xor(z2, off);
                z3 += __shfl_xor(z3, off);
            }
        }

        // gates (replicated across the 16 lanes of the chunk group)
        const float ig = sigmoidf_(z0 + xv0);
        const float fg = sigmoidf_(z1 + xv1);
        const float gg = tanhf(z2 + xv2);
        const float og = sigmoidf_(z3 + xv3);
        cst = fg * cst + ig * gg;
        const float hval = og * tanhf(cst);

        // publish h slice (one lane per element group)
        if (cchunk == 0)
            hout[(size_t)t * HID + e] = hval;

        __syncthreads();   // drains h stores (vmcnt 0) across all 8 waves

        if (tid == 0) {
            __builtin_amdgcn_fence(__ATOMIC_RELEASE, "agent");   // wb L2 -> LLC
            __hip_atomic_store(flgd + wg * 16, (unsigned)(s + 1),
                               __ATOMIC_RELAXED, __HIP_MEMORY_SCOPE_AGENT);
        }

        // prefetch next step's xw while we poll (read-only data, any epoch ok)
        {
            const int sn = (s + 1 < S_LEN) ? s + 1 : s;
            const int tn = dir ? (S_LEN - 1 - sn) : sn;
            const float* xp = xw + (size_t)tn * G4 + e;
            xv0 = xp[0];
            xv1 = xp[512];
            xv2 = xp[1024];
            xv3 = xp[1536];
        }

        if (s + 1 < S_LEN) {
            if (w == 0) {
                if (ln < KWG) {
                    const unsigned su = (unsigned)(s + 1);
                    const unsigned* fp = flgd + ln * 16;
                    while (__hip_atomic_load(fp, __ATOMIC_RELAXED,
                                             __HIP_MEMORY_SCOPE_AGENT) < su)
                        __builtin_amdgcn_s_sleep(1);
                }
                __builtin_amdgcn_fence(__ATOMIC_ACQUIRE, "agent");  // inv L1/L2
            }
            __syncthreads();   // release all waves to read fresh h
        }
    }
}

// ---------------------------------------------------------------------------
// Kernel 3: scores[t] = blstm[t] . attn_w + attn_b
// ---------------------------------------------------------------------------
__global__ __launch_bounds__(256) void score_kernel(const float* __restrict__ hf,
                                                    const float* __restrict__ hb,
                                                    const float* __restrict__ aw,
                                                    const float* __restrict__ ab,
                                                    float* __restrict__ scores)
{
    const int t = blockIdx.x;
    const int tid = threadIdx.x;
    float p = hf[(size_t)t * HID + tid] * aw[tid]
            + hf[(size_t)t * HID + 256 + tid] * aw[256 + tid]
            + hb[(size_t)t * HID + tid] * aw[512 + tid]
            + hb[(size_t)t * HID + 256 + tid] * aw[768 + tid];
#pragma unroll
    for (int off = 1; off < 64; off <<= 1) p += __shfl_xor(p, off);
    __shared__ float rsum[4];
    if ((tid & 63) == 0) rsum[tid >> 6] = p;
    __syncthreads();
    if (tid == 0) scores[t] = rsum[0] + rsum[1] + rsum[2] + rsum[3] + ab[0];
}

// ---------------------------------------------------------------------------
// Kernel 4: per-entity masked softmax over span scores + weighted sum of blstm
// ---------------------------------------------------------------------------
__global__ __launch_bounds__(256) void entity_kernel(const int* __restrict__ eidx,
                                                     const float* __restrict__ scores,
                                                     const float* __restrict__ hf,
                                                     const float* __restrict__ hb,
                                                     float* __restrict__ out)
{
    const int e = blockIdx.x;
    const int tid = threadIdx.x;
    __shared__ float wsh[NL];
    __shared__ int ish[NL];
    if (tid < 32) {
        const int l = tid;
        const int ix = (l < NL) ? eidx[e * NL + l] : -1;
        const float sc = (ix >= 0) ? scores[ix] : -1e9f;
        float mx = sc;
#pragma unroll
        for (int off = 1; off < 32; off <<= 1) mx = fmaxf(mx, __shfl_xor(mx, off));
        const float ex = (ix >= 0) ? expf(sc - mx) : 0.f;
        float sm = ex;
#pragma unroll
        for (int off = 1; off < 32; off <<= 1) sm += __shfl_xor(sm, off);
        if (l < NL) {
            wsh[l] = ex / sm;
            ish[l] = (ix >= 0) ? ix : 0;
        }
    }
    __syncthreads();
    for (int d0 = tid; d0 < 1024; d0 += 256) {
        const float* hsrc = (d0 < HID) ? hf : hb;
        const int dd = d0 & (HID - 1);
        float a = 0.f;
#pragma unroll
        for (int l = 0; l < NL; ++l) a += wsh[l] * hsrc[(size_t)ish[l] * HID + dd];
        out[(size_t)e * 1024 + d0] = a;
    }
}

// ---------------------------------------------------------------------------
extern "C" void kernel_launch(void* const* d_in, const int* in_sizes, int n_in,
                              void* d_out, int out_size, void* d_ws, size_t ws_size,
                              hipStream_t stream)
{
    const int*   sentence = (const int*)d_in[0];
    const int*   eidx     = (const int*)d_in[1];
    const float* emb      = (const float*)d_in[2];
    const float* Wi_f     = (const float*)d_in[3];
    const float* Wh_f     = (const float*)d_in[4];
    const float* b_f      = (const float*)d_in[5];
    const float* Wi_b     = (const float*)d_in[6];
    const float* Wh_b     = (const float*)d_in[7];
    const float* b_b      = (const float*)d_in[8];
    const float* attn_w   = (const float*)d_in[9];
    const float* attn_b   = (const float*)d_in[10];
    float* out = (float*)d_out;
    float* ws  = (float*)d_ws;

    // workspace layout (floats): xwf | xwb | hf | hb | scores | flags
    const size_t XW = (size_t)S_LEN * G4;
    const size_t HS = (size_t)S_LEN * HID;
    float* xwf = ws;
    float* xwb = ws + XW;
    float* hf  = ws + 2 * XW;
    float* hb  = ws + 2 * XW + HS;
    float* sc  = ws + 2 * XW + 2 * HS;
    unsigned* flg = (unsigned*)(ws + 2 * XW + 2 * HS + S_LEN);

    hipMemsetAsync(flg, 0, 2 * KWG * 16 * sizeof(unsigned), stream);
    xw_gemm<<<dim3(256, 2, 2), dim3(256), 0, stream>>>(sentence, emb, Wi_f, b_f, Wi_b, b_b, xwf, xwb);
    lstm_kernel<<<dim3(2 * KWG), dim3(512), 0, stream>>>(xwf, xwb, Wh_f, Wh_b, hf, hb, flg);
    score_kernel<<<dim3(S_LEN), dim3(256), 0, stream>>>(hf, hb, attn_w, attn_b, sc);
    entity_kernel<<<dim3(NE), dim3(256), 0, stream>>>(eidx, sc, hf, hb, out);
}